// Round 6
// baseline (4273.599 us; speedup 1.0000x reference)
//
#include <hip/hip_runtime.h>
#include <math.h>

// DGM Black-Scholes PDE residual via forward-mode jets.
// Channels c: 0 = value; 1 = d/dt; 2..6 = d/dx1..dx5; 7..11 = d2/dx1^2..dx5^2.
// One wave (= one block, 64 lanes) per sample; lane l owns hidden units 2l, 2l+1.
// A_S / A_P (LDS, [128][16] floats each) hold hidden-state jet rows (S, and S*R).
// The 6 constant tx header rows (one-hot first derivs, zero 2nd derivs) are
// folded into every gate matmul from registers.
// Gate order R -> H -> Z -> G with incremental combine keeps only 2 jet sets +
// accumulator live during any matmul (~150 VGPR peak).
// Gate matmuls software-pipeline: A-rows 2 ahead (LDS ~120cyc), W 4 rows ahead
// (L1/L2 ~100-200cyc), all slots statically named.
// NOTE: macro params must avoid vector member names (.x/.y/.z/.w) — R4 compile
// failure was `w` param substituting into `a0.w`.

namespace {
constexpr int HID_ = 128;
constexpr int NCH  = 12;
constexpr int ASTR = 16;     // LDS row stride in floats (12 used, 64B rows)
constexpr float MU_   = 0.05f;
constexpr float HSIG2 = 0.5f * 0.2f * 0.2f;  // 0.02
}

#define LOADA(AB, h, A0, A1, A2) do {                                     \
    const float4* _A4 = reinterpret_cast<const float4*>((AB)[(h)]);       \
    A0 = _A4[0]; A1 = _A4[1]; A2 = _A4[2]; } while (0)

#define LOADW(h, Wv) do {                                                 \
    Wv = *reinterpret_cast<const float2*>(Wb + (size_t)(h) * HID_); } while (0)

#define FMA12(A0, A1, A2, Wv) do {                                        \
    acc0[0]  = fmaf((A0).x, (Wv).x, acc0[0]);  acc1[0]  = fmaf((A0).x, (Wv).y, acc1[0]);  \
    acc0[1]  = fmaf((A0).y, (Wv).x, acc0[1]);  acc1[1]  = fmaf((A0).y, (Wv).y, acc1[1]);  \
    acc0[2]  = fmaf((A0).z, (Wv).x, acc0[2]);  acc1[2]  = fmaf((A0).z, (Wv).y, acc1[2]);  \
    acc0[3]  = fmaf((A0).w, (Wv).x, acc0[3]);  acc1[3]  = fmaf((A0).w, (Wv).y, acc1[3]);  \
    acc0[4]  = fmaf((A1).x, (Wv).x, acc0[4]);  acc1[4]  = fmaf((A1).x, (Wv).y, acc1[4]);  \
    acc0[5]  = fmaf((A1).y, (Wv).x, acc0[5]);  acc1[5]  = fmaf((A1).y, (Wv).y, acc1[5]);  \
    acc0[6]  = fmaf((A1).z, (Wv).x, acc0[6]);  acc1[6]  = fmaf((A1).z, (Wv).y, acc1[6]);  \
    acc0[7]  = fmaf((A1).w, (Wv).x, acc0[7]);  acc1[7]  = fmaf((A1).w, (Wv).y, acc1[7]);  \
    acc0[8]  = fmaf((A2).x, (Wv).x, acc0[8]);  acc1[8]  = fmaf((A2).x, (Wv).y, acc1[8]);  \
    acc0[9]  = fmaf((A2).y, (Wv).x, acc0[9]);  acc1[9]  = fmaf((A2).y, (Wv).y, acc1[9]);  \
    acc0[10] = fmaf((A2).z, (Wv).x, acc0[10]); acc1[10] = fmaf((A2).z, (Wv).y, acc1[10]); \
    acc0[11] = fmaf((A2).w, (Wv).x, acc0[11]); acc1[11] = fmaf((A2).w, (Wv).y, acc1[11]); \
} while (0)

__global__ __launch_bounds__(64, 3)
void dgm_pde(const float* __restrict__ t,
             const float* __restrict__ x,
             const float* __restrict__ Win,    // [6][128]
             const float* __restrict__ b_in,   // [128]
             const float* __restrict__ Wg,     // [3][4][134][128]
             const float* __restrict__ bg,     // [3][4][128]
             const float* __restrict__ Wout,   // [128]
             const float* __restrict__ bout,   // [1]
             float* __restrict__ out)          // [B]
{
    __shared__ __align__(16) float A_S[HID_][ASTR];   // S jets
    __shared__ __align__(16) float A_P[HID_][ASTR];   // S*R jets
    const int l    = threadIdx.x;     // 0..63, single wave per block
    const int samp = blockIdx.x;
    const int j0   = 2 * l;

    // ---- tx ----
    float tx[6];
    tx[0] = t[samp];
    #pragma unroll
    for (int m = 1; m < 6; ++m) tx[m] = x[samp * 5 + m - 1];

    // ---- input layer: S = tanh(tx @ Win + b_in), jet-propagated ----
    float S0[NCH], S1[NCH];
    {
        float w0[6], w1[6];
        #pragma unroll
        for (int m = 0; m < 6; ++m) {
            const float2 ww = *reinterpret_cast<const float2*>(Win + m * HID_ + j0);
            w0[m] = ww.x; w1[m] = ww.y;
        }
        const float2 bb = *reinterpret_cast<const float2*>(b_in + j0);
        float p0 = bb.x, p1 = bb.y;
        #pragma unroll
        for (int m = 0; m < 6; ++m) { p0 = fmaf(tx[m], w0[m], p0); p1 = fmaf(tx[m], w1[m], p1); }
        const float v0 = tanhf(p0), v1 = tanhf(p1);
        const float t20 = 1.f - v0 * v0, t21 = 1.f - v1 * v1;
        S0[0] = v0; S1[0] = v1;
        #pragma unroll
        for (int m = 0; m < 6; ++m) { S0[1 + m] = t20 * w0[m]; S1[1 + m] = t21 * w1[m]; }
        #pragma unroll
        for (int k = 1; k <= 5; ++k) {
            S0[6 + k] = -2.f * v0 * t20 * w0[k] * w0[k];
            S1[6 + k] = -2.f * v1 * t21 * w1[k] * w1[k];
        }
    }

    // ---- helpers ----
    auto storeJ = [&](float (*AB)[ASTR], const float* a0, const float* a1) {
        #pragma unroll
        for (int c = 0; c < NCH; c += 4) {
            *reinterpret_cast<float4*>(&AB[j0][c])     = make_float4(a0[c], a0[c+1], a0[c+2], a0[c+3]);
            *reinterpret_cast<float4*>(&AB[j0 + 1][c]) = make_float4(a1[c], a1[c+1], a1[c+2], a1[c+3]);
        }
    };
    // Gate matmul over K = 6 (register header) + 128 (LDS jet rows), pipelined.
    auto matmul = [&](const float (*Ab)[ASTR],
                      const float* __restrict__ Wgt, const float* __restrict__ bgt,
                      float* __restrict__ acc0, float* __restrict__ acc1) {
        #pragma unroll
        for (int c = 1; c < NCH; ++c) { acc0[c] = 0.f; acc1[c] = 0.f; }
        {
            const float2 bb = *reinterpret_cast<const float2*>(bgt + j0);
            acc0[0] = bb.x; acc1[0] = bb.y;
        }
        // header rows: value ch += tx[m]*w; first-deriv ch (1+m) += w; 2nd derivs 0
        #pragma unroll
        for (int m = 0; m < 6; ++m) {
            const float2 wh = *reinterpret_cast<const float2*>(Wgt + m * HID_ + j0);
            acc0[0] = fmaf(tx[m], wh.x, acc0[0]);
            acc1[0] = fmaf(tx[m], wh.y, acc1[0]);
            acc0[1 + m] += wh.x; acc1[1 + m] += wh.y;
        }
        const float* Wb = Wgt + 6 * HID_ + j0;   // body weights, row stride HID_
        float4 pa0, pa1, pa2, qa0, qa1, qa2;
        float2 wr0, wr1, wr2, wr3;
        LOADW(0, wr0); LOADW(1, wr1); LOADW(2, wr2); LOADW(3, wr3);
        LOADA(Ab, 0, pa0, pa1, pa2);
        LOADA(Ab, 1, qa0, qa1, qa2);
        #pragma unroll 4
        for (int h = 0; h + 5 < HID_; h += 2) {
            float4 na0, na1, na2, ma0, ma1, ma2;
            float2 t0, t1;
            LOADA(Ab, h + 2, na0, na1, na2);
            LOADA(Ab, h + 3, ma0, ma1, ma2);
            LOADW(h + 4, t0); LOADW(h + 5, t1);
            FMA12(pa0, pa1, pa2, wr0);
            FMA12(qa0, qa1, qa2, wr1);
            pa0 = na0; pa1 = na1; pa2 = na2;
            qa0 = ma0; qa1 = ma1; qa2 = ma2;
            wr0 = wr2; wr1 = wr3; wr2 = t0; wr3 = t1;
        }
        // loop exits after h=122: FMAs done through row 123; pa/qa = rows 124,125;
        // wr0..wr3 = W rows 124..127.
        float4 na0, na1, na2, ma0, ma1, ma2;
        LOADA(Ab, 126, na0, na1, na2);
        LOADA(Ab, 127, ma0, ma1, ma2);
        FMA12(pa0, pa1, pa2, wr0);
        FMA12(qa0, qa1, qa2, wr1);
        FMA12(na0, na1, na2, wr2);
        FMA12(ma0, ma1, ma2, wr3);
    };
    auto act = [&](float* a) {  // in-place tanh jet: 2nd derivs first (read 1st + value)
        const float v  = tanhf(a[0]);
        const float t2 = 1.f - v * v;
        #pragma unroll
        for (int k = 1; k <= 5; ++k) a[6 + k] = t2 * a[6 + k] - 2.f * v * t2 * a[1 + k] * a[1 + k];
        #pragma unroll
        for (int m = 0; m < 6; ++m) a[1 + m] = t2 * a[1 + m];
        a[0] = v;
    };
    // in-place jet product a <- s (.) a  (dd first, then d, then value)
    auto prodS = [&](const float* s, float* a) {
        #pragma unroll
        for (int k = 1; k <= 5; ++k)
            a[6+k] = s[6+k]*a[0] + 2.f*s[1+k]*a[1+k] + s[0]*a[6+k];
        #pragma unroll
        for (int m = 0; m < 6; ++m)
            a[1+m] = s[1+m]*a[0] + s[0]*a[1+m];
        a[0] = s[0]*a[0];
    };

    storeJ(A_S, S0, S1);
    __syncthreads();

    // ---- 3 DGM layers, order R -> H -> Z -> G (register-pressure-minimal) ----
    float Zc0[NCH], Zc1[NCH], Rc0[NCH], Rc1[NCH];
    constexpr int GSTride = 134 * HID_;
    #pragma unroll 1
    for (int layer = 0; layer < 3; ++layer) {
        const float* WL = Wg + (size_t)layer * 4 * GSTride;
        const float* bL = bg + layer * 4 * HID_;

        // R gate
        matmul(A_S, WL + 2 * GSTride, bL + 2 * HID_, Rc0, Rc1);
        act(Rc0); act(Rc1);
        prodS(S0, Rc0); prodS(S1, Rc1);          // Rc <- S (.) R
        __syncthreads();
        storeJ(A_P, Rc0, Rc1);                   // A_P = S*R jets
        __syncthreads();

        // H gate (reads A_P); result in Rc
        matmul(A_P, WL + 3 * GSTride, bL + 3 * HID_, Rc0, Rc1);
        act(Rc0); act(Rc1);                      // Rc = H jets

        // Z gate (reads A_S)
        matmul(A_S, WL + 0 * GSTride, bL + 0 * HID_, Zc0, Zc1);
        act(Zc0); act(Zc1);
        prodS(S0, Zc0); prodS(S1, Zc1);          // Zc <- Z (.) S ; S regs now dead

        // G gate (reads A_S); accumulate into freed S registers
        matmul(A_S, WL + 1 * GSTride, bL + 1 * HID_, S0, S1);
        act(S0); act(S1);                        // S arrays = G jets

        // Snew = Zc + (1-G)(.)H, in place into S (dd, d, value order)
        #pragma unroll
        for (int k = 1; k <= 5; ++k) {
            S0[6+k] = Zc0[6+k] + (1.f - S0[0])*Rc0[6+k] - S0[6+k]*Rc0[0] - 2.f*S0[1+k]*Rc0[1+k];
            S1[6+k] = Zc1[6+k] + (1.f - S1[0])*Rc1[6+k] - S1[6+k]*Rc1[0] - 2.f*S1[1+k]*Rc1[1+k];
        }
        #pragma unroll
        for (int m = 0; m < 6; ++m) {
            S0[1+m] = Zc0[1+m] + (1.f - S0[0])*Rc0[1+m] - S0[1+m]*Rc0[0];
            S1[1+m] = Zc1[1+m] + (1.f - S1[0])*Rc1[1+m] - S1[1+m]*Rc1[0];
        }
        S0[0] = Zc0[0] + (1.f - S0[0])*Rc0[0];
        S1[0] = Zc1[0] + (1.f - S1[0])*Rc1[0];

        __syncthreads();          // A_S (S jets) reads complete
        storeJ(A_S, S0, S1);
        __syncthreads();
    }

    // ---- PDE residual epilogue ----
    float comb0 = S0[1] - MU_ * S0[0];
    float comb1 = S1[1] - MU_ * S1[0];
    #pragma unroll
    for (int k = 1; k <= 5; ++k) {
        comb0 += MU_ * tx[k] * S0[1 + k] + HSIG2 * S0[6 + k];
        comb1 += MU_ * tx[k] * S1[1 + k] + HSIG2 * S1[6 + k];
    }
    const float2 wo = *reinterpret_cast<const float2*>(Wout + j0);
    float part = comb0 * wo.x + comb1 * wo.y;
    #pragma unroll
    for (int off = 32; off > 0; off >>= 1) part += __shfl_xor(part, off, 64);
    if (l == 0) out[samp] = part - MU_ * bout[0];
}

extern "C" void kernel_launch(void* const* d_in, const int* in_sizes, int n_in,
                              void* d_out, int out_size, void* d_ws, size_t ws_size,
                              hipStream_t stream)
{
    const float* t    = (const float*)d_in[0];
    const float* x    = (const float*)d_in[1];
    const float* Win  = (const float*)d_in[2];
    const float* b_in = (const float*)d_in[3];
    const float* Wg   = (const float*)d_in[4];
    const float* bg   = (const float*)d_in[5];
    const float* Wout = (const float*)d_in[6];
    const float* bout = (const float*)d_in[7];
    float* out = (float*)d_out;

    const int nB = in_sizes[0];   // 32768 samples
    dgm_pde<<<nB, 64, 0, stream>>>(t, x, Win, b_in, Wg, bg, Wout, bout, out);
}

// Round 10
// 3206.623 us; speedup vs baseline: 1.3327x; 1.3327x over previous
//
#include <hip/hip_runtime.h>
#include <math.h>

// DGM Black-Scholes PDE residual via forward-mode jets.
// Channels c: 0 = value; 1 = d/dt; 2..6 = d/dx1..dx5; 7..11 = d2/dx1^2..dx5^2.
// Structure = the measured-good R2 kernel (2680 us, no spill): 4 samples/block,
// one wave per sample, lane l owns hidden units 2l,2l+1; A (LDS [128][16] f32)
// holds hidden jet rows; 6 constant tx header rows folded in from registers.
// SINGLE delta vs R2: 4-deep W register ring in the matmul body (prefetch W
// rows h+4,h+5 per 2-row step) to hide ~200cyc L2 latency on weight streams.
// R6 lesson: stacked pipeline rewrite spilled to scratch (WRITE_SIZE 5.4 GB);
// detect spills via FETCH/WRITE_SIZE, not VGPR_Count.
// R4 lesson: macro params must avoid vector member names (.x/.y/.z/.w).

namespace {
constexpr int HID_ = 128;
constexpr int NCH  = 12;
constexpr int ASTR = 16;     // LDS row stride in floats (12 used, 64B rows)
constexpr int SPB  = 4;      // samples (waves) per block
constexpr float MU_   = 0.05f;
constexpr float HSIG2 = 0.5f * 0.2f * 0.2f;  // 0.02
}

// One body-row FMA: unpack A-row (3x float4) and accumulate 12 channels.
// acc0/acc1 are the enclosing matmul's accumulator arrays.
#define FMAROW(Ap, Wv) do {                                                    \
    const float4* _A4 = reinterpret_cast<const float4*>(Ap);                   \
    const float4 _a0 = _A4[0], _a1 = _A4[1], _a2 = _A4[2];                     \
    acc0[0]  = fmaf(_a0.x, (Wv).x, acc0[0]);  acc1[0]  = fmaf(_a0.x, (Wv).y, acc1[0]);  \
    acc0[1]  = fmaf(_a0.y, (Wv).x, acc0[1]);  acc1[1]  = fmaf(_a0.y, (Wv).y, acc1[1]);  \
    acc0[2]  = fmaf(_a0.z, (Wv).x, acc0[2]);  acc1[2]  = fmaf(_a0.z, (Wv).y, acc1[2]);  \
    acc0[3]  = fmaf(_a0.w, (Wv).x, acc0[3]);  acc1[3]  = fmaf(_a0.w, (Wv).y, acc1[3]);  \
    acc0[4]  = fmaf(_a1.x, (Wv).x, acc0[4]);  acc1[4]  = fmaf(_a1.x, (Wv).y, acc1[4]);  \
    acc0[5]  = fmaf(_a1.y, (Wv).x, acc0[5]);  acc1[5]  = fmaf(_a1.y, (Wv).y, acc1[5]);  \
    acc0[6]  = fmaf(_a1.z, (Wv).x, acc0[6]);  acc1[6]  = fmaf(_a1.z, (Wv).y, acc1[6]);  \
    acc0[7]  = fmaf(_a1.w, (Wv).x, acc0[7]);  acc1[7]  = fmaf(_a1.w, (Wv).y, acc1[7]);  \
    acc0[8]  = fmaf(_a2.x, (Wv).x, acc0[8]);  acc1[8]  = fmaf(_a2.x, (Wv).y, acc1[8]);  \
    acc0[9]  = fmaf(_a2.y, (Wv).x, acc0[9]);  acc1[9]  = fmaf(_a2.y, (Wv).y, acc1[9]);  \
    acc0[10] = fmaf(_a2.z, (Wv).x, acc0[10]); acc1[10] = fmaf(_a2.z, (Wv).y, acc1[10]); \
    acc0[11] = fmaf(_a2.w, (Wv).x, acc0[11]); acc1[11] = fmaf(_a2.w, (Wv).y, acc1[11]); \
} while (0)

__global__ __launch_bounds__(64 * SPB, 3)
void dgm_pde(const float* __restrict__ t,
             const float* __restrict__ x,
             const float* __restrict__ Win,    // [6][128]
             const float* __restrict__ b_in,   // [128]
             const float* __restrict__ Wg,     // [3][4][134][128]
             const float* __restrict__ bg,     // [3][4][128]
             const float* __restrict__ Wout,   // [128]
             const float* __restrict__ bout,   // [1]
             float* __restrict__ out)          // [B]
{
    __shared__ __align__(16) float Abuf[SPB][HID_][ASTR];
    const int wv   = threadIdx.x >> 6;
    const int l    = threadIdx.x & 63;
    const int samp = blockIdx.x * SPB + wv;
    float (*A)[ASTR] = Abuf[wv];
    const int j0 = 2 * l;

    // ---- tx ----
    float tx[6];
    tx[0] = t[samp];
    #pragma unroll
    for (int m = 1; m < 6; ++m) tx[m] = x[samp * 5 + m - 1];

    // ---- input layer: S = tanh(tx @ Win + b_in), jet-propagated ----
    float S0[NCH], S1[NCH];
    {
        float w0[6], w1[6];
        #pragma unroll
        for (int m = 0; m < 6; ++m) {
            const float2 ww = *reinterpret_cast<const float2*>(Win + m * HID_ + j0);
            w0[m] = ww.x; w1[m] = ww.y;
        }
        const float2 bb = *reinterpret_cast<const float2*>(b_in + j0);
        float p0 = bb.x, p1 = bb.y;
        #pragma unroll
        for (int m = 0; m < 6; ++m) { p0 = fmaf(tx[m], w0[m], p0); p1 = fmaf(tx[m], w1[m], p1); }
        const float v0 = tanhf(p0), v1 = tanhf(p1);
        const float t20 = 1.f - v0 * v0, t21 = 1.f - v1 * v1;
        S0[0] = v0; S1[0] = v1;
        #pragma unroll
        for (int m = 0; m < 6; ++m) { S0[1 + m] = t20 * w0[m]; S1[1 + m] = t21 * w1[m]; }
        #pragma unroll
        for (int k = 1; k <= 5; ++k) {
            S0[6 + k] = -2.f * v0 * t20 * w0[k] * w0[k];
            S1[6 + k] = -2.f * v1 * t21 * w1[k] * w1[k];
        }
    }

    // ---- helpers ----
    auto storeA = [&](const float* a0, const float* a1) {
        #pragma unroll
        for (int c = 0; c < NCH; c += 4) {
            *reinterpret_cast<float4*>(&A[j0][c])     = make_float4(a0[c], a0[c+1], a0[c+2], a0[c+3]);
            *reinterpret_cast<float4*>(&A[j0 + 1][c]) = make_float4(a1[c], a1[c+1], a1[c+2], a1[c+3]);
        }
    };
    // Gate matmul over K = 6 (register header) + 128 (LDS jet rows).
    // W register-ring: rows h..h+3 resident, prefetch h+4,h+5 per 2-row step.
    auto matmul = [&](const float* __restrict__ Wgt, const float* __restrict__ bgt,
                      float* __restrict__ acc0, float* __restrict__ acc1) {
        #pragma unroll
        for (int c = 1; c < NCH; ++c) { acc0[c] = 0.f; acc1[c] = 0.f; }
        {
            const float2 bb = *reinterpret_cast<const float2*>(bgt + j0);
            acc0[0] = bb.x; acc1[0] = bb.y;
        }
        // header rows: value ch += tx[m]*w; first-deriv ch (1+m) += w; 2nd derivs 0
        #pragma unroll
        for (int m = 0; m < 6; ++m) {
            const float2 wh = *reinterpret_cast<const float2*>(Wgt + m * HID_ + j0);
            acc0[0] = fmaf(tx[m], wh.x, acc0[0]);
            acc1[0] = fmaf(tx[m], wh.y, acc1[0]);
            acc0[1 + m] += wh.x; acc1[1 + m] += wh.y;
        }
        const float* Wb = Wgt + 6 * HID_ + j0;   // body weights, row stride HID_
        float2 wr0 = *reinterpret_cast<const float2*>(Wb + 0 * HID_);
        float2 wr1 = *reinterpret_cast<const float2*>(Wb + 1 * HID_);
        float2 wr2 = *reinterpret_cast<const float2*>(Wb + 2 * HID_);
        float2 wr3 = *reinterpret_cast<const float2*>(Wb + 3 * HID_);
        // invariant at loop top: wr0..wr3 = W rows h..h+3
        #pragma unroll 2
        for (int h = 0; h < HID_ - 4; h += 2) {
            const float2 wn0 = *reinterpret_cast<const float2*>(Wb + (size_t)(h + 4) * HID_);
            const float2 wn1 = *reinterpret_cast<const float2*>(Wb + (size_t)(h + 5) * HID_);
            FMAROW(A[h],     wr0);
            FMAROW(A[h + 1], wr1);
            wr0 = wr2; wr1 = wr3; wr2 = wn0; wr3 = wn1;
        }
        // exit with wr0..wr3 = W rows 124..127
        FMAROW(A[124], wr0);
        FMAROW(A[125], wr1);
        FMAROW(A[126], wr2);
        FMAROW(A[127], wr3);
    };
    auto act = [&](float* a) {  // in-place tanh jet: 2nd derivs first (read 1st + value)
        const float v  = tanhf(a[0]);
        const float t2 = 1.f - v * v;
        #pragma unroll
        for (int k = 1; k <= 5; ++k) a[6 + k] = t2 * a[6 + k] - 2.f * v * t2 * a[1 + k] * a[1 + k];
        #pragma unroll
        for (int m = 0; m < 6; ++m) a[1 + m] = t2 * a[1 + m];
        a[0] = v;
    };

    storeA(S0, S1);
    __syncthreads();

    // ---- 3 DGM layers (R2 order: Z, G, R, then H) ----
    float Z0[NCH], Z1[NCH], G0[NCH], G1[NCH], R0[NCH], R1[NCH];
    constexpr int GSTride = 134 * HID_;
    #pragma unroll 1
    for (int layer = 0; layer < 3; ++layer) {
        const float* WL = Wg + (size_t)layer * 4 * GSTride;
        const float* bL = bg + layer * 4 * HID_;

        matmul(WL + 0 * GSTride, bL + 0 * HID_, Z0, Z1); act(Z0); act(Z1);
        matmul(WL + 1 * GSTride, bL + 1 * HID_, G0, G1); act(G0); act(G1);
        matmul(WL + 2 * GSTride, bL + 2 * HID_, R0, R1); act(R0); act(R1);

        // P = S (.) R jet product, in place into R: dd first, then d, then value
        #pragma unroll
        for (int k = 1; k <= 5; ++k) {
            R0[6+k] = S0[6+k]*R0[0] + 2.f*S0[1+k]*R0[1+k] + S0[0]*R0[6+k];
            R1[6+k] = S1[6+k]*R1[0] + 2.f*S1[1+k]*R1[1+k] + S1[0]*R1[6+k];
        }
        #pragma unroll
        for (int m = 0; m < 6; ++m) {
            R0[1+m] = S0[1+m]*R0[0] + S0[0]*R0[1+m];
            R1[1+m] = S1[1+m]*R1[0] + S1[0]*R1[1+m];
        }
        R0[0] = S0[0]*R0[0];
        R1[0] = S1[0]*R1[0];

        __syncthreads();          // A (S jets) reads complete
        storeA(R0, R1);           // A now holds S*R jets
        __syncthreads();

        matmul(WL + 3 * GSTride, bL + 3 * HID_, R0, R1); act(R0); act(R1);  // H in R

        // Snew = (1-G)(.)H + Z(.)S, in place into S: dd, d, value order
        #pragma unroll
        for (int k = 1; k <= 5; ++k) {
            S0[6+k] = (1.f - G0[0])*R0[6+k] - G0[6+k]*R0[0] - 2.f*G0[1+k]*R0[1+k]
                    + Z0[6+k]*S0[0] + 2.f*Z0[1+k]*S0[1+k] + Z0[0]*S0[6+k];
            S1[6+k] = (1.f - G1[0])*R1[6+k] - G1[6+k]*R1[0] - 2.f*G1[1+k]*R1[1+k]
                    + Z1[6+k]*S1[0] + 2.f*Z1[1+k]*S1[1+k] + Z1[0]*S1[6+k];
        }
        #pragma unroll
        for (int m = 0; m < 6; ++m) {
            S0[1+m] = (1.f - G0[0])*R0[1+m] - G0[1+m]*R0[0] + Z0[1+m]*S0[0] + Z0[0]*S0[1+m];
            S1[1+m] = (1.f - G1[0])*R1[1+m] - G1[1+m]*R1[0] + Z1[1+m]*S1[0] + Z1[0]*S1[1+m];
        }
        S0[0] = (1.f - G0[0])*R0[0] + Z0[0]*S0[0];
        S1[0] = (1.f - G1[0])*R1[0] + Z1[0]*S1[0];

        __syncthreads();          // A (S*R jets) reads complete
        storeA(S0, S1);
        __syncthreads();
    }

    // ---- PDE residual epilogue ----
    float comb0 = S0[1] - MU_ * S0[0];
    float comb1 = S1[1] - MU_ * S1[0];
    #pragma unroll
    for (int k = 1; k <= 5; ++k) {
        comb0 += MU_ * tx[k] * S0[1 + k] + HSIG2 * S0[6 + k];
        comb1 += MU_ * tx[k] * S1[1 + k] + HSIG2 * S1[6 + k];
    }
    const float2 wo = *reinterpret_cast<const float2*>(Wout + j0);
    float part = comb0 * wo.x + comb1 * wo.y;
    #pragma unroll
    for (int off = 32; off > 0; off >>= 1) part += __shfl_xor(part, off, 64);
    if (l == 0) out[samp] = part - MU_ * bout[0];
}

extern "C" void kernel_launch(void* const* d_in, const int* in_sizes, int n_in,
                              void* d_out, int out_size, void* d_ws, size_t ws_size,
                              hipStream_t stream)
{
    const float* t    = (const float*)d_in[0];
    const float* x    = (const float*)d_in[1];
    const float* Win  = (const float*)d_in[2];
    const float* b_in = (const float*)d_in[3];
    const float* Wg   = (const float*)d_in[4];
    const float* bg   = (const float*)d_in[5];
    const float* Wout = (const float*)d_in[6];
    const float* bout = (const float*)d_in[7];
    float* out = (float*)d_out;

    const int nB = in_sizes[0];   // 32768, divisible by SPB
    dgm_pde<<<nB / SPB, 64 * SPB, 0, stream>>>(t, x, Win, b_in, Wg, bg, Wout, bout, out);
}